// Round 7
// baseline (2108.891 us; speedup 1.0000x reference)
//
#include <hip/hip_runtime.h>

// ---------------------------------------------------------------------------
// 2-layer LSTM (B=256,T=1024,in=64,H=128) + fused FC(128->32), bf16 MFMA.
// Layer-pipelined: 128 blocks = 64 L0 + 64 L1 concurrent; L1 lags L0 by 2
// chunks (CH=16), handoff via global out0 + agent-scope release/acquire.
// R7: (a) odd-dword LDS row stride (APAD=AK+10) -> bank-conflict-free frag
// reads & h-writes; (b) MFMA cluster reordered gates->FC->accX before EW so
// independent MFMAs hide the gate chain's latency; setprio(1) around MFMAs.
// ---------------------------------------------------------------------------

static constexpr int B   = 256;
static constexpr int T   = 1024;
static constexpr int H   = 128;
static constexpr int O   = 32;
static constexpr int R   = 4;         // batch rows per block
static constexpr int NBL = B / R;     // 64 blocks per layer
static constexpr int CH  = 16;        // steps per pipeline chunk
static constexpr int NCH = T / CH;

typedef __attribute__((ext_vector_type(8))) short  short8;
typedef __attribute__((ext_vector_type(4))) float  f32x4;

#define LOG2E 1.4426950408889634f

#if __has_builtin(__builtin_amdgcn_exp2f)
#define EXP2(x) __builtin_amdgcn_exp2f(x)
#else
#define EXP2(x) __expf((x) * 0.69314718056f)
#endif
#if __has_builtin(__builtin_amdgcn_rcpf)
#define RCP(x) __builtin_amdgcn_rcpf(x)
#else
#define RCP(x) (1.0f / (x))
#endif

__device__ __forceinline__ unsigned short f2bf(float f) {
  unsigned int u = __builtin_bit_cast(unsigned int, f);
  u += 0x7fffu + ((u >> 16) & 1u);        // round-to-nearest-even
  return (unsigned short)(u >> 16);
}

__device__ __forceinline__ float sigm(float x) {
  return RCP(1.0f + EXP2(-LOG2E * x));
}
__device__ __forceinline__ float tanh_f(float x) {
  return 1.0f - 2.0f * RCP(1.0f + EXP2(2.0f * LOG2E * x));
}

// LDS-only barrier: wait own ds ops, then s_barrier. Global ops float.
__device__ __forceinline__ void block_sync_lds() {
  __builtin_amdgcn_sched_barrier(0);
  asm volatile("s_waitcnt lgkmcnt(0)" ::: "memory");
  __builtin_amdgcn_s_barrier();
  __builtin_amdgcn_sched_barrier(0);
}

// ---------------------------------------------------------------------------
// One layer's full-T scan for R=4 batch rows. 8 waves; wave w owns gate cols
// [w*16,w*16+16) of each gate block (i,f,g,o). Lane owns 1 C-row (reg 0).
// LDS buffer A[buf] at iter t holds {h(t-1), x(t+1)}; accX = bias + x@Wih is
// computed one step ahead; gates = mfma(h, Whh, C=accX).
// ---------------------------------------------------------------------------
template <int KIN, bool IN_BF16, bool WRITE_HOUT, bool FUSE_FC, bool PROD, bool CONS>
__device__ __forceinline__ void scan_body(
    unsigned short* __restrict__ Ash,
    const void* __restrict__ in_,            // [B,T,KIN] f32 (L0) / bf16 (L1)
    const float* __restrict__ h0,            // [B,H] layer slice
    const float* __restrict__ c0,            // [B,H] layer slice
    const float* __restrict__ Wih,           // [4H,KIN]
    const float* __restrict__ Whh,           // [4H,H]
    const float* __restrict__ bih,           // [4H]
    const float* __restrict__ bhh,           // [4H]
    unsigned short* __restrict__ hout,       // bf16 [B,T,H] (L0 only)
    float* __restrict__ hN,                  // [B,H]
    float* __restrict__ cN,                  // [B,H]
    const float* __restrict__ Wfc,           // [32,128] (L1 only)
    const float* __restrict__ bfc,           // [32]
    float* __restrict__ fco,                 // [B,T,32]
    int* __restrict__ flag, const int bbase)
{
  constexpr int AK   = KIN + H;              // 192 or 256
  constexpr int KCX  = KIN / 32;             // 2 or 4
  constexpr int KCH  = H / 32;               // 4
  constexpr int APAD = AK + 10;              // row stride: 101 / 133 dwords (odd)

  const int tid  = threadIdx.x;
  const int w    = tid >> 6;
  const int l    = tid & 63;
  const int l15  = l & 15;
  const int lhi  = l >> 4;
  const int jcol = w * 16 + l15;

#define AEL(buf, row, col) Ash[(((buf) * 16 + (row)) * APAD) + (col)]

  // ---- gate-weight fragments, split x-part / h-part ----
  short8 wfx[4][KCX], wfh[4][KCH];
  float  bias4[4];
#pragma unroll
  for (int gb = 0; gb < 4; ++gb) {
    const int gc = gb * H + jcol;
    const float* wi = Wih + (size_t)gc * KIN;
    const float* wh = Whh + (size_t)gc * H;
#pragma unroll
    for (int kc = 0; kc < KCX; ++kc) {
      const float* s = wi + kc * 32 + lhi * 8;
      float4 a = *(const float4*)s;
      float4 b = *(const float4*)(s + 4);
      short8 v;
      v[0] = (short)f2bf(a.x); v[1] = (short)f2bf(a.y);
      v[2] = (short)f2bf(a.z); v[3] = (short)f2bf(a.w);
      v[4] = (short)f2bf(b.x); v[5] = (short)f2bf(b.y);
      v[6] = (short)f2bf(b.z); v[7] = (short)f2bf(b.w);
      wfx[gb][kc] = v;
    }
#pragma unroll
    for (int kc = 0; kc < KCH; ++kc) {
      const float* s = wh + kc * 32 + lhi * 8;
      float4 a = *(const float4*)s;
      float4 b = *(const float4*)(s + 4);
      short8 v;
      v[0] = (short)f2bf(a.x); v[1] = (short)f2bf(a.y);
      v[2] = (short)f2bf(a.z); v[3] = (short)f2bf(a.w);
      v[4] = (short)f2bf(b.x); v[5] = (short)f2bf(b.y);
      v[6] = (short)f2bf(b.z); v[7] = (short)f2bf(b.w);
      wfh[gb][kc] = v;
    }
    bias4[gb] = bih[gc] + bhh[gc];
  }

  // ---- FC weight fragments (waves 0,1) ----
  short8 bfr[4];
  float fcbias = 0.f;
  if constexpr (FUSE_FC) {
    const int oc = (w & 1) * 16 + l15;
#pragma unroll
    for (int kc = 0; kc < 4; ++kc) {
      const float* s = Wfc + (size_t)oc * H + kc * 32 + lhi * 8;
      float4 a = *(const float4*)s;
      float4 b = *(const float4*)(s + 4);
      short8 v;
      v[0] = (short)f2bf(a.x); v[1] = (short)f2bf(a.y);
      v[2] = (short)f2bf(a.z); v[3] = (short)f2bf(a.w);
      v[4] = (short)f2bf(b.x); v[5] = (short)f2bf(b.y);
      v[6] = (short)f2bf(b.z); v[7] = (short)f2bf(b.w);
      bfr[kc] = v;
    }
    fcbias = bfc[oc];
  }

  // lane owns batch row (bbase + lhi), tile row lhi*4, acc reg 0
  float cst   = c0[(size_t)(bbase + lhi) * H + jcol];
  float hlast = 0.f;

  const float*          inf = (const float*)in_;
  const unsigned short* inb = (const unsigned short*)in_;

  // staging coords: 128 lanes, 32 lanes/row
  const bool sact = tid < 128;
  const int  srow = (tid >> 5) & 3;
  int scol;
  if constexpr (!IN_BF16) scol = (tid * 2) & 63;
  else                    scol = (tid * 4) & 127;
  const int srm = srow * 4;                  // tile row = 4*b
  const float*          xpf = inf + (size_t)(bbase + srow) * T * KIN + scol;
  const unsigned short* xpb = inb + (size_t)(bbase + srow) * T * KIN + scol;

  unsigned short* hp = nullptr;
  if constexpr (WRITE_HOUT)
    hp = hout + (size_t)(bbase + lhi) * T * H + jcol;
  float* fp = nullptr;
  if constexpr (FUSE_FC)
    fp = fco + (size_t)(bbase + lhi) * T * O + (w & 1) * 16 + l15;

  // ---- zero both A buffers once (garbage rows stay 0 forever) ----
  for (int i = tid; i < 16 * APAD; i += 512)
    ((unsigned int*)Ash)[i] = 0u;
  __syncthreads();

  // ---- consumer: wait for chunks 0,1 before touching in_ ----
  if constexpr (CONS) {
    if (tid == 0) {
      while (__hip_atomic_load(flag, __ATOMIC_ACQUIRE, __HIP_MEMORY_SCOPE_AGENT) < 2)
        __builtin_amdgcn_s_sleep(4);
    }
    __syncthreads();
  }

  // ---- prologue ----
  // A[1].x <- x(0) (consumed below for accX_0);  A[0].x <- x(1);  A[0].h <- h0
  if (sact) {
    if constexpr (!IN_BF16) {
      float2 v0 = *(const float2*)xpf;
      float2 v1 = *(const float2*)(xpf + KIN);
      *(unsigned int*)&AEL(1, srm, scol) =
          (unsigned int)f2bf(v0.x) | ((unsigned int)f2bf(v0.y) << 16);
      *(unsigned int*)&AEL(0, srm, scol) =
          (unsigned int)f2bf(v1.x) | ((unsigned int)f2bf(v1.y) << 16);
    } else {
      uint2 v0 = *(const uint2*)xpb;
      uint2 v1 = *(const uint2*)(xpb + KIN);
      *(uint2*)&AEL(1, srm, scol) = v0;
      *(uint2*)&AEL(0, srm, scol) = v1;
    }
  }
  if (tid < 128) {
    const int row = tid >> 5, col = (tid * 4) & 127;
    float4 v = *(const float4*)(h0 + (size_t)(bbase + row) * H + col);
    uint2 p;
    p.x = (unsigned int)f2bf(v.x) | ((unsigned int)f2bf(v.y) << 16);
    p.y = (unsigned int)f2bf(v.z) | ((unsigned int)f2bf(v.w) << 16);
    *(uint2*)&AEL(0, row * 4, KIN + col) = p;
  }

  float2 pfoF = {0.f, 0.f}; uint2 pfoB = {0u, 0u};   // holds x(t+2) at iter t
  if (sact) {
    if constexpr (!IN_BF16) pfoF = *(const float2*)(xpf + 2 * (size_t)KIN);
    else                    pfoB = *(const uint2*)(xpb + 2 * (size_t)KIN);
  }
  xpf += 3 * (size_t)KIN;                            // points at x(3)
  xpb += 3 * (size_t)KIN;
  __syncthreads();

  // accX_0 = bias + x(0) @ Wih^T  (x(0) frags from A[1].x)
  f32x4 accX[4];
  {
    short8 afx[KCX];
#pragma unroll
    for (int kc = 0; kc < KCX; ++kc)
      afx[kc] = *(const short8*)&AEL(1, l15, kc * 32 + lhi * 8);
#pragma unroll
    for (int gb = 0; gb < 4; ++gb) {
      f32x4 a = {bias4[gb], bias4[gb], bias4[gb], bias4[gb]};
#pragma unroll
      for (int kc = 0; kc < KCX; ++kc)
        a = __builtin_amdgcn_mfma_f32_16x16x32_bf16(afx[kc], wfx[gb][kc], a, 0, 0, 0);
      accX[gb] = a;
    }
  }
  __syncthreads();   // protect A[1].x (just read) from iter-0 writes

  int cur = 0;
  for (int k = 0; k < NCH; ++k) {
    if constexpr (CONS) {
      if (k > 0) {
        const int want = (k + 2 > NCH) ? NCH : (k + 2);
        if (tid == 0) {
          while (__hip_atomic_load(flag, __ATOMIC_ACQUIRE, __HIP_MEMORY_SCOPE_AGENT) < want)
            __builtin_amdgcn_s_sleep(4);
        }
        __syncthreads();
      }
    }

    for (int tt = 0; tt < CH; ++tt) {
      const int t   = k * CH + tt;
      const int nxt = cur ^ 1;

      // issue load of x(t+3); store x(t+2)=pf_old (load retired a step ago)
      float2 pfnF = {0.f, 0.f}; uint2 pfnB = {0u, 0u};
      if (sact) {
        if constexpr (!IN_BF16) {
          pfnF = *(const float2*)xpf;
          *(unsigned int*)&AEL(nxt, srm, scol) =
              (unsigned int)f2bf(pfoF.x) | ((unsigned int)f2bf(pfoF.y) << 16);
        } else {
          pfnB = *(const uint2*)xpb;
          *(uint2*)&AEL(nxt, srm, scol) = pfoB;
        }
      }

      // h(t-1) fragments, then x(t+1) fragments
      short8 afh[KCH];
#pragma unroll
      for (int kc = 0; kc < KCH; ++kc)
        afh[kc] = *(const short8*)&AEL(cur, l15, KIN + kc * 32 + lhi * 8);
      short8 afx[KCX];
#pragma unroll
      for (int kc = 0; kc < KCX; ++kc)
        afx[kc] = *(const short8*)&AEL(cur, l15, kc * 32 + lhi * 8);

      __builtin_amdgcn_s_setprio(1);
      // gates(t) = accX(t) + h(t-1) @ Whh^T
      f32x4 acc[4];
#pragma unroll
      for (int gb = 0; gb < 4; ++gb) {
        f32x4 a = accX[gb];
#pragma unroll
        for (int kc = 0; kc < KCH; ++kc)
          a = __builtin_amdgcn_mfma_f32_16x16x32_bf16(afh[kc], wfh[gb][kc], a, 0, 0, 0);
        acc[gb] = a;
      }

      // fused FC for step t-1 from h(t-1) frags
      f32x4 fs = {fcbias, fcbias, fcbias, fcbias};
      if constexpr (FUSE_FC) {
        if (w < 2 && t > 0) {
#pragma unroll
          for (int kc = 0; kc < 4; ++kc)
            fs = __builtin_amdgcn_mfma_f32_16x16x32_bf16(afh[kc], bfr[kc], fs, 0, 0, 0);
        }
      }

      // accX(t+1) = bias + x(t+1) @ Wih^T  -- independent MFMAs issued here
      // so the gate chain's latency drains under them, before EW reads acc.
#pragma unroll
      for (int gb = 0; gb < 4; ++gb) {
        f32x4 a = {bias4[gb], bias4[gb], bias4[gb], bias4[gb]};
#pragma unroll
        for (int kc = 0; kc < KCX; ++kc)
          a = __builtin_amdgcn_mfma_f32_16x16x32_bf16(afx[kc], wfx[gb][kc], a, 0, 0, 0);
        accX[gb] = a;
      }
      __builtin_amdgcn_s_setprio(0);

      // elementwise: single row per lane (tile row lhi*4, batch bbase+lhi)
      {
        float i_ = sigm(acc[0][0]);
        float f_ = sigm(acc[1][0]);
        float g_ = tanh_f(acc[2][0]);
        float o_ = sigm(acc[3][0]);
        float c_ = f_ * cst + i_ * g_;
        cst = c_;
        float hn = o_ * tanh_f(c_);
        hlast = hn;
        unsigned short hb = f2bf(hn);
        AEL(nxt, lhi * 4, KIN + jcol) = hb;
        if constexpr (WRITE_HOUT) { hp[0] = hb; }
      }
      if constexpr (WRITE_HOUT) hp += H;

      if constexpr (FUSE_FC) {
        if (w < 2 && t > 0)
          fp[(size_t)(t - 1) * O] = fs[0];
      }

      // LDS-only sync: global ops float across steps
      block_sync_lds();
      cur = nxt;
      if constexpr (!IN_BF16) pfoF = pfnF; else pfoB = pfnB;
      if (t <= T - 5) { xpf += KIN; xpb += KIN; }
    }

    if constexpr (PROD) {
      // drain own global stores, barrier, then agent-scope release.
      __builtin_amdgcn_sched_barrier(0);
      asm volatile("s_waitcnt vmcnt(0)" ::: "memory");
      __builtin_amdgcn_s_barrier();
      if (tid == 0)
        __hip_atomic_store(flag, k + 1, __ATOMIC_RELEASE, __HIP_MEMORY_SCOPE_AGENT);
    }
  }

  // ---- tails ----
  {
    const size_t b = bbase + lhi;
    hN[b * H + jcol] = hlast;
    cN[b * H + jcol] = cst;
  }
  if constexpr (FUSE_FC) {
    if (w < 2) {   // FC for final step T-1 from A[cur] h-slot = h(T-1)
      short8 a4[4];
#pragma unroll
      for (int kc = 0; kc < 4; ++kc)
        a4[kc] = *(const short8*)&AEL(cur, l15, KIN + kc * 32 + lhi * 8);
      f32x4 fs = {fcbias, fcbias, fcbias, fcbias};
#pragma unroll
      for (int kc = 0; kc < 4; ++kc)
        fs = __builtin_amdgcn_mfma_f32_16x16x32_bf16(a4[kc], bfr[kc], fs, 0, 0, 0);
      fp[(size_t)(T - 1) * O] = fs[0];
    }
  }
#undef AEL
}

// ---------------------------------------------------------------------------
__global__ __launch_bounds__(512, 2) void lstm_fused(
    const float* __restrict__ x,
    const float* __restrict__ h0, const float* __restrict__ c0,
    const float* __restrict__ Wih0, const float* __restrict__ Whh0,
    const float* __restrict__ bih0, const float* __restrict__ bhh0,
    const float* __restrict__ Wih1, const float* __restrict__ Whh1,
    const float* __restrict__ bih1, const float* __restrict__ bhh1,
    const float* __restrict__ fcw, const float* __restrict__ fcb,
    unsigned short* __restrict__ out0,
    float* __restrict__ out, float* __restrict__ hN, float* __restrict__ cN,
    int* __restrict__ flags)
{
  __shared__ __align__(16) unsigned short Ash[2 * 16 * 266];
  const int bid = blockIdx.x;
  if (bid < NBL) {
    // L0 producer
    scan_body<64, false, true, false, true, false>(
        Ash, x, h0, c0, Wih0, Whh0, bih0, bhh0,
        out0, hN, cN, nullptr, nullptr, nullptr,
        flags + bid, bid * R);
  } else {
    // L1 consumer + fused FC
    const int rb = bid - NBL;
    scan_body<128, true, false, true, false, true>(
        Ash, out0, h0 + B * H, c0 + B * H, Wih1, Whh1, bih1, bhh1,
        nullptr, hN + B * H, cN + B * H, fcw, fcb, out,
        flags + rb, rb * R);
  }
}

// ---------------------------------------------------------------------------
extern "C" void kernel_launch(void* const* d_in, const int* in_sizes, int n_in,
                              void* d_out, int out_size, void* d_ws, size_t ws_size,
                              hipStream_t stream) {
  (void)in_sizes; (void)n_in; (void)out_size; (void)ws_size;

  const float* x    = (const float*)d_in[0];
  const float* h0   = (const float*)d_in[1];
  const float* c0   = (const float*)d_in[2];
  const float* Wih0 = (const float*)d_in[3];
  const float* Whh0 = (const float*)d_in[4];
  const float* bih0 = (const float*)d_in[5];
  const float* bhh0 = (const float*)d_in[6];
  const float* Wih1 = (const float*)d_in[7];
  const float* Whh1 = (const float*)d_in[8];
  const float* bih1 = (const float*)d_in[9];
  const float* bhh1 = (const float*)d_in[10];
  const float* fcw  = (const float*)d_in[11];
  const float* fcb  = (const float*)d_in[12];

  int*            flags = (int*)d_ws;                             // 64 ints
  unsigned short* out0  = (unsigned short*)((char*)d_ws + 1024);  // bf16 [B,T,H]

  float* out = (float*)d_out;                                     // [B,T,32]
  float* hN  = out + (size_t)B * T * O;                           // [2,B,H]
  float* cN  = hN + (size_t)2 * B * H;                            // [2,B,H]

  hipMemsetAsync(d_ws, 0, 1024, stream);   // reset pipeline flags every launch
  lstm_fused<<<2 * NBL, 512, 0, stream>>>(
      x, h0, c0, Wih0, Whh0, bih0, bhh0, Wih1, Whh1, bih1, bhh1,
      fcw, fcb, out0, out, hN, cN, flags);
}

// Round 8
// 825.800 us; speedup vs baseline: 2.5538x; 2.5538x over previous
//
#include <hip/hip_runtime.h>

// ---------------------------------------------------------------------------
// 2-layer LSTM (B=256,T=1024,in=64,H=128) + fused FC(128->32), bf16 MFMA.
// Layer-pipelined: 128 blocks = 64 L0 + 64 L1 concurrent; L1 lags L0 by 2
// chunks (CH=16), handoff via global out0 + agent-scope release/acquire.
// R8 (vs R6): x-operand loaded per-wave straight into registers (no LDS
// staging/reads for x; inactive lanes read a zero pad in d_ws); h kept in an
// 8KB fragment-contiguous LDS layout -> all ds_read_b128 are 16B-aligned and
// bank-conflict-free (R7's odd-stride misalignment lesson applied).
// ---------------------------------------------------------------------------

static constexpr int B   = 256;
static constexpr int T   = 1024;
static constexpr int H   = 128;
static constexpr int O   = 32;
static constexpr int R   = 4;         // batch rows per block
static constexpr int NBL = B / R;     // 64 blocks per layer
static constexpr int CH  = 16;        // steps per pipeline chunk
static constexpr int NCH = T / CH;

typedef __attribute__((ext_vector_type(8))) short  short8;
typedef __attribute__((ext_vector_type(4))) float  f32x4;

#define LOG2E 1.4426950408889634f

#if __has_builtin(__builtin_amdgcn_exp2f)
#define EXP2(x) __builtin_amdgcn_exp2f(x)
#else
#define EXP2(x) __expf((x) * 0.69314718056f)
#endif
#if __has_builtin(__builtin_amdgcn_rcpf)
#define RCP(x) __builtin_amdgcn_rcpf(x)
#else
#define RCP(x) (1.0f / (x))
#endif

__device__ __forceinline__ unsigned short f2bf(float f) {
  unsigned int u = __builtin_bit_cast(unsigned int, f);
  u += 0x7fffu + ((u >> 16) & 1u);        // round-to-nearest-even
  return (unsigned short)(u >> 16);
}

__device__ __forceinline__ float sigm(float x) {
  return RCP(1.0f + EXP2(-LOG2E * x));
}
__device__ __forceinline__ float tanh_f(float x) {
  return 1.0f - 2.0f * RCP(1.0f + EXP2(2.0f * LOG2E * x));
}

// LDS-only barrier: wait own ds ops, then s_barrier. Global ops float.
__device__ __forceinline__ void block_sync_lds() {
  __builtin_amdgcn_sched_barrier(0);
  asm volatile("s_waitcnt lgkmcnt(0)" ::: "memory");
  __builtin_amdgcn_s_barrier();
  __builtin_amdgcn_sched_barrier(0);
}

// ---------------------------------------------------------------------------
// One layer's full-T scan for R=4 batch rows. 8 waves; wave w owns gate cols
// [w*16,w*16+16) of each gate block (i,f,g,o). Lane owns 1 C-row (reg 0).
// h lives in frag-contiguous LDS (dbuf, 4KB each): addr = buf*2048 + kc*512 +
// fraglane*8 + j (shorts). x never touches LDS: active lanes (l15%4==0) load
// their 16B A-frag of x(t+2) from global each step (2-step reg pipeline).
// ---------------------------------------------------------------------------
template <int KIN, bool IN_BF16, bool WRITE_HOUT, bool FUSE_FC, bool PROD, bool CONS>
__device__ __forceinline__ void scan_body(
    unsigned short* __restrict__ Ash,        // 2*2048 shorts
    const void* __restrict__ in_,            // [B,T,KIN] f32 (L0) / bf16 (L1)
    const float* __restrict__ h0,            // [B,H] layer slice
    const float* __restrict__ c0,            // [B,H] layer slice
    const float* __restrict__ Wih,           // [4H,KIN]
    const float* __restrict__ Whh,           // [4H,H]
    const float* __restrict__ bih,           // [4H]
    const float* __restrict__ bhh,           // [4H]
    unsigned short* __restrict__ hout,       // bf16 [B,T,H] (L0 only)
    float* __restrict__ hN,                  // [B,H]
    float* __restrict__ cN,                  // [B,H]
    const float* __restrict__ Wfc,           // [32,128] (L1 only)
    const float* __restrict__ bfc,           // [32]
    float* __restrict__ fco,                 // [B,T,32]
    const void* __restrict__ zpad,           // 512B zeroed global pad
    int* __restrict__ flag, const int bbase)
{
  constexpr int KCX  = KIN / 32;             // 2 or 4
  constexpr int KCH  = H / 32;               // 4
  constexpr int HBUF = KCH * 512;            // 2048 shorts per buffer

  const int tid  = threadIdx.x;
  const int w    = tid >> 6;
  const int l    = tid & 63;
  const int l15  = l & 15;
  const int lhi  = l >> 4;
  const int jcol = w * 16 + l15;

  // ---- gate-weight fragments, split x-part / h-part ----
  short8 wfx[4][KCX], wfh[4][KCH];
  float  bias4[4];
#pragma unroll
  for (int gb = 0; gb < 4; ++gb) {
    const int gc = gb * H + jcol;
    const float* wi = Wih + (size_t)gc * KIN;
    const float* wh = Whh + (size_t)gc * H;
#pragma unroll
    for (int kc = 0; kc < KCX; ++kc) {
      const float* s = wi + kc * 32 + lhi * 8;
      float4 a = *(const float4*)s;
      float4 b = *(const float4*)(s + 4);
      short8 v;
      v[0] = (short)f2bf(a.x); v[1] = (short)f2bf(a.y);
      v[2] = (short)f2bf(a.z); v[3] = (short)f2bf(a.w);
      v[4] = (short)f2bf(b.x); v[5] = (short)f2bf(b.y);
      v[6] = (short)f2bf(b.z); v[7] = (short)f2bf(b.w);
      wfx[gb][kc] = v;
    }
#pragma unroll
    for (int kc = 0; kc < KCH; ++kc) {
      const float* s = wh + kc * 32 + lhi * 8;
      float4 a = *(const float4*)s;
      float4 b = *(const float4*)(s + 4);
      short8 v;
      v[0] = (short)f2bf(a.x); v[1] = (short)f2bf(a.y);
      v[2] = (short)f2bf(a.z); v[3] = (short)f2bf(a.w);
      v[4] = (short)f2bf(b.x); v[5] = (short)f2bf(b.y);
      v[6] = (short)f2bf(b.z); v[7] = (short)f2bf(b.w);
      wfh[gb][kc] = v;
    }
    bias4[gb] = bih[gc] + bhh[gc];
  }

  // ---- FC weight fragments (waves 0,1) ----
  short8 bfr[4];
  float fcbias = 0.f;
  if constexpr (FUSE_FC) {
    const int oc = (w & 1) * 16 + l15;
#pragma unroll
    for (int kc = 0; kc < 4; ++kc) {
      const float* s = Wfc + (size_t)oc * H + kc * 32 + lhi * 8;
      float4 a = *(const float4*)s;
      float4 b = *(const float4*)(s + 4);
      short8 v;
      v[0] = (short)f2bf(a.x); v[1] = (short)f2bf(a.y);
      v[2] = (short)f2bf(a.z); v[3] = (short)f2bf(a.w);
      v[4] = (short)f2bf(b.x); v[5] = (short)f2bf(b.y);
      v[6] = (short)f2bf(b.z); v[7] = (short)f2bf(b.w);
      bfr[kc] = v;
    }
    fcbias = bfc[oc];
  }

  // lane owns batch row (bbase + lhi), tile row lhi*4, acc reg 0
  float cst   = c0[(size_t)(bbase + lhi) * H + jcol];
  float hlast = 0.f;

  // h-write slot (frag-contiguous layout), constant per lane:
  // element (tile_row=lhi*4, hidden=jcol)
  const int hws = (jcol >> 5) * 512 +
                  (lhi * 4 + 16 * ((w & 1) * 2 + (l15 >> 3))) * 8 + (jcol & 7);

  // ---- per-lane x source (A-frag direct from global) ----
  const bool xact = (l15 & 3) == 0;          // rows 0,4,8,12 are real
  const int  br   = l15 >> 2;                // batch row 0..3
  const float*          xf = nullptr;
  const unsigned short* xb = nullptr;
  size_t xstep;
  if constexpr (!IN_BF16) {
    xf = xact ? ((const float*)in_ + (size_t)(bbase + br) * T * KIN + lhi * 8)
              : (const float*)zpad;
    xstep = xact ? (size_t)KIN : 0;
  } else {
    xb = xact ? ((const unsigned short*)in_ + (size_t)(bbase + br) * T * KIN + lhi * 8)
              : (const unsigned short*)zpad;
    xstep = xact ? (size_t)KIN : 0;
  }

  unsigned short* hp = nullptr;
  if constexpr (WRITE_HOUT)
    hp = hout + (size_t)(bbase + lhi) * T * H + jcol;
  float* fp = nullptr;
  if constexpr (FUSE_FC)
    fp = fco + (size_t)(bbase + lhi) * T * O + (w & 1) * 16 + l15;

  // ---- zero both h buffers once (padding rows stay 0 forever) ----
  for (int i = tid; i < HBUF; i += 512)      // 2*HBUF shorts = HBUF uints
    ((unsigned int*)Ash)[i] = 0u;
  __syncthreads();

  // ---- consumer: wait for chunks 0,1 before touching in_ ----
  if constexpr (CONS) {
    if (tid == 0) {
      while (__hip_atomic_load(flag, __ATOMIC_ACQUIRE, __HIP_MEMORY_SCOPE_AGENT) < 2)
        __builtin_amdgcn_s_sleep(4);
    }
    __syncthreads();
  }

  // ---- prologue: h0 into buffer 0; x(0)->accX0; x(1)->xc ----
  Ash[hws] = f2bf(h0[(size_t)(bbase + lhi) * H + jcol]);

  f32x4 accX[4];
  float4 xcF[2 * KCX]; short8 xcB[KCX];      // x(t+1) register pipeline
  if constexpr (!IN_BF16) {
    float4 x0[2 * KCX];
#pragma unroll
    for (int kc = 0; kc < KCX; ++kc) {
      x0[2 * kc]     = *(const float4*)(xf + kc * 32);
      x0[2 * kc + 1] = *(const float4*)(xf + kc * 32 + 4);
    }
    xf += xstep;
#pragma unroll
    for (int kc = 0; kc < KCX; ++kc) {
      xcF[2 * kc]     = *(const float4*)(xf + kc * 32);
      xcF[2 * kc + 1] = *(const float4*)(xf + kc * 32 + 4);
    }
    xf += xstep;
    short8 fr[KCX];
#pragma unroll
    for (int kc = 0; kc < KCX; ++kc) {
      float4 a = x0[2 * kc], b = x0[2 * kc + 1];
      short8 v;
      v[0] = (short)f2bf(a.x); v[1] = (short)f2bf(a.y);
      v[2] = (short)f2bf(a.z); v[3] = (short)f2bf(a.w);
      v[4] = (short)f2bf(b.x); v[5] = (short)f2bf(b.y);
      v[6] = (short)f2bf(b.z); v[7] = (short)f2bf(b.w);
      fr[kc] = v;
    }
#pragma unroll
    for (int gb = 0; gb < 4; ++gb) {
      f32x4 a = {bias4[gb], bias4[gb], bias4[gb], bias4[gb]};
#pragma unroll
      for (int kc = 0; kc < KCX; ++kc)
        a = __builtin_amdgcn_mfma_f32_16x16x32_bf16(fr[kc], wfx[gb][kc], a, 0, 0, 0);
      accX[gb] = a;
    }
  } else {
    short8 x0[KCX];
#pragma unroll
    for (int kc = 0; kc < KCX; ++kc) x0[kc] = *(const short8*)(xb + kc * 32);
    xb += xstep;
#pragma unroll
    for (int kc = 0; kc < KCX; ++kc) xcB[kc] = *(const short8*)(xb + kc * 32);
    xb += xstep;
#pragma unroll
    for (int gb = 0; gb < 4; ++gb) {
      f32x4 a = {bias4[gb], bias4[gb], bias4[gb], bias4[gb]};
#pragma unroll
      for (int kc = 0; kc < KCX; ++kc)
        a = __builtin_amdgcn_mfma_f32_16x16x32_bf16(x0[kc], wfx[gb][kc], a, 0, 0, 0);
      accX[gb] = a;
    }
  }
  __syncthreads();                           // h0 writes visible to all

  int cur = 0;
  for (int k = 0; k < NCH; ++k) {
    if constexpr (CONS) {
      if (k > 0) {
        const int want = (k + 2 > NCH) ? NCH : (k + 2);
        if (tid == 0) {
          while (__hip_atomic_load(flag, __ATOMIC_ACQUIRE, __HIP_MEMORY_SCOPE_AGENT) < want)
            __builtin_amdgcn_s_sleep(4);
        }
        __syncthreads();
      }
    }

    for (int tt = 0; tt < CH; ++tt) {
      const int t   = k * CH + tt;
      const int nxt = cur ^ 1;

      // issue x(t+2) loads (consumed NEXT step -> full-step latency slack)
      float4 xnF[2 * KCX]; short8 xnB[KCX];
      if constexpr (!IN_BF16) {
#pragma unroll
        for (int kc = 0; kc < KCX; ++kc) {
          xnF[2 * kc]     = *(const float4*)(xf + kc * 32);
          xnF[2 * kc + 1] = *(const float4*)(xf + kc * 32 + 4);
        }
      } else {
#pragma unroll
        for (int kc = 0; kc < KCX; ++kc) xnB[kc] = *(const short8*)(xb + kc * 32);
      }

      // h(t-1) fragments: conflict-free 16B-aligned reads at lane*16
      short8 afh[KCH];
#pragma unroll
      for (int kc = 0; kc < KCH; ++kc)
        afh[kc] = *(const short8*)&Ash[cur * HBUF + kc * 512 + l * 8];

      // gates(t) = accX(t) + h(t-1) @ Whh^T   (4-deep dependent chain)
      f32x4 acc[4];
#pragma unroll
      for (int gb = 0; gb < 4; ++gb) {
        f32x4 a = accX[gb];
#pragma unroll
        for (int kc = 0; kc < KCH; ++kc)
          a = __builtin_amdgcn_mfma_f32_16x16x32_bf16(afh[kc], wfh[gb][kc], a, 0, 0, 0);
        acc[gb] = a;
      }

      // fused FC for step t-1 from h(t-1) frags
      f32x4 fs = {fcbias, fcbias, fcbias, fcbias};
      if constexpr (FUSE_FC) {
        if (w < 2 && t > 0) {
#pragma unroll
          for (int kc = 0; kc < 4; ++kc)
            fs = __builtin_amdgcn_mfma_f32_16x16x32_bf16(afh[kc], bfr[kc], fs, 0, 0, 0);
        }
      }

      // accX(t+1) from register x(t+1): independent MFMAs issued here so the
      // gate chain's latency drains under them before EW reads acc.
      if constexpr (!IN_BF16) {
        short8 fr[KCX];
#pragma unroll
        for (int kc = 0; kc < KCX; ++kc) {
          float4 a = xcF[2 * kc], b = xcF[2 * kc + 1];
          short8 v;
          v[0] = (short)f2bf(a.x); v[1] = (short)f2bf(a.y);
          v[2] = (short)f2bf(a.z); v[3] = (short)f2bf(a.w);
          v[4] = (short)f2bf(b.x); v[5] = (short)f2bf(b.y);
          v[6] = (short)f2bf(b.z); v[7] = (short)f2bf(b.w);
          fr[kc] = v;
        }
#pragma unroll
        for (int gb = 0; gb < 4; ++gb) {
          f32x4 a = {bias4[gb], bias4[gb], bias4[gb], bias4[gb]};
#pragma unroll
          for (int kc = 0; kc < KCX; ++kc)
            a = __builtin_amdgcn_mfma_f32_16x16x32_bf16(fr[kc], wfx[gb][kc], a, 0, 0, 0);
          accX[gb] = a;
        }
      } else {
#pragma unroll
        for (int gb = 0; gb < 4; ++gb) {
          f32x4 a = {bias4[gb], bias4[gb], bias4[gb], bias4[gb]};
#pragma unroll
          for (int kc = 0; kc < KCX; ++kc)
            a = __builtin_amdgcn_mfma_f32_16x16x32_bf16(xcB[kc], wfx[gb][kc], a, 0, 0, 0);
          accX[gb] = a;
        }
      }

      // elementwise: single row per lane (tile row lhi*4, batch bbase+lhi)
      {
        float i_ = sigm(acc[0][0]);
        float f_ = sigm(acc[1][0]);
        float g_ = tanh_f(acc[2][0]);
        float o_ = sigm(acc[3][0]);
        float c_ = f_ * cst + i_ * g_;
        cst = c_;
        float hn = o_ * tanh_f(c_);
        hlast = hn;
        unsigned short hb = f2bf(hn);
        Ash[nxt * HBUF + hws] = hb;
        if constexpr (WRITE_HOUT) { hp[0] = hb; }
      }
      if constexpr (WRITE_HOUT) hp += H;

      if constexpr (FUSE_FC) {
        if (w < 2 && t > 0)
          fp[(size_t)(t - 1) * O] = fs[0];
      }

      // rotate x register pipeline; advance pointer (uniform clamp at tail)
      if constexpr (!IN_BF16) {
#pragma unroll
        for (int q = 0; q < 2 * KCX; ++q) xcF[q] = xnF[q];
        if (t <= T - 4) xf += xstep;
      } else {
#pragma unroll
        for (int q = 0; q < KCX; ++q) xcB[q] = xnB[q];
        if (t <= T - 4) xb += xstep;
      }

      // LDS-only sync: global ops float across steps
      block_sync_lds();
      cur = nxt;
    }

    if constexpr (PROD) {
      // drain own global stores, barrier, then agent-scope release.
      __builtin_amdgcn_sched_barrier(0);
      asm volatile("s_waitcnt vmcnt(0)" ::: "memory");
      __builtin_amdgcn_s_barrier();
      if (tid == 0)
        __hip_atomic_store(flag, k + 1, __ATOMIC_RELEASE, __HIP_MEMORY_SCOPE_AGENT);
    }
  }

  // ---- tails ----
  {
    const size_t b = bbase + lhi;
    hN[b * H + jcol] = hlast;
    cN[b * H + jcol] = cst;
  }
  if constexpr (FUSE_FC) {
    if (w < 2) {   // FC for final step T-1 from h(T-1) frags in Ash[cur]
      short8 a4[4];
#pragma unroll
      for (int kc = 0; kc < 4; ++kc)
        a4[kc] = *(const short8*)&Ash[cur * HBUF + kc * 512 + l * 8];
      f32x4 fs = {fcbias, fcbias, fcbias, fcbias};
#pragma unroll
      for (int kc = 0; kc < 4; ++kc)
        fs = __builtin_amdgcn_mfma_f32_16x16x32_bf16(a4[kc], bfr[kc], fs, 0, 0, 0);
      fp[(size_t)(T - 1) * O] = fs[0];
    }
  }
}

// ---------------------------------------------------------------------------
__global__ __launch_bounds__(512, 2) void lstm_fused(
    const float* __restrict__ x,
    const float* __restrict__ h0, const float* __restrict__ c0,
    const float* __restrict__ Wih0, const float* __restrict__ Whh0,
    const float* __restrict__ bih0, const float* __restrict__ bhh0,
    const float* __restrict__ Wih1, const float* __restrict__ Whh1,
    const float* __restrict__ bih1, const float* __restrict__ bhh1,
    const float* __restrict__ fcw, const float* __restrict__ fcb,
    unsigned short* __restrict__ out0,
    float* __restrict__ out, float* __restrict__ hN, float* __restrict__ cN,
    int* __restrict__ flags, const void* __restrict__ zpad)
{
  __shared__ __align__(16) unsigned short Ash[2 * 2048];   // 8KB, h only
  const int bid = blockIdx.x;
  if (bid < NBL) {
    // L0 producer
    scan_body<64, false, true, false, true, false>(
        Ash, x, h0, c0, Wih0, Whh0, bih0, bhh0,
        out0, hN, cN, nullptr, nullptr, nullptr, zpad,
        flags + bid, bid * R);
  } else {
    // L1 consumer + fused FC
    const int rb = bid - NBL;
    scan_body<128, true, false, true, false, true>(
        Ash, out0, h0 + B * H, c0 + B * H, Wih1, Whh1, bih1, bhh1,
        nullptr, hN + B * H, cN + B * H, fcw, fcb, out, zpad,
        flags + rb, rb * R);
  }
}

// ---------------------------------------------------------------------------
extern "C" void kernel_launch(void* const* d_in, const int* in_sizes, int n_in,
                              void* d_out, int out_size, void* d_ws, size_t ws_size,
                              hipStream_t stream) {
  (void)in_sizes; (void)n_in; (void)out_size; (void)ws_size;

  const float* x    = (const float*)d_in[0];
  const float* h0   = (const float*)d_in[1];
  const float* c0   = (const float*)d_in[2];
  const float* Wih0 = (const float*)d_in[3];
  const float* Whh0 = (const float*)d_in[4];
  const float* bih0 = (const float*)d_in[5];
  const float* bhh0 = (const float*)d_in[6];
  const float* Wih1 = (const float*)d_in[7];
  const float* Whh1 = (const float*)d_in[8];
  const float* bih1 = (const float*)d_in[9];
  const float* bhh1 = (const float*)d_in[10];
  const float* fcw  = (const float*)d_in[11];
  const float* fcb  = (const float*)d_in[12];

  int*            flags = (int*)d_ws;                             // 64 ints
  const void*     zpad  = (const void*)((char*)d_ws + 512);       // 512B zeros
  unsigned short* out0  = (unsigned short*)((char*)d_ws + 1024);  // bf16 [B,T,H]

  float* out = (float*)d_out;                                     // [B,T,32]
  float* hN  = out + (size_t)B * T * O;                           // [2,B,H]
  float* cN  = hN + (size_t)2 * B * H;                            // [2,B,H]

  hipMemsetAsync(d_ws, 0, 1024, stream);   // reset flags + zero pad each launch
  lstm_fused<<<2 * NBL, 512, 0, stream>>>(
      x, h0, c0, Wih0, Whh0, bih0, bhh0, Wih1, Whh1, bih1, bhh1,
      fcw, fcb, out0, out, hN, cN, flags, zpad);
}